// Round 1
// baseline (1004.461 us; speedup 1.0000x reference)
//
#include <hip/hip_runtime.h>
#include <hip/hip_bf16.h>

typedef __attribute__((ext_vector_type(8))) short bf16x8;
typedef __attribute__((ext_vector_type(4))) float f32x4;

__device__ inline short f2bf(float f) {
    __hip_bfloat16 h = __float2bfloat16(f);
    short s;
    __builtin_memcpy(&s, &h, 2);
    return s;
}

// ---------------- cast kernels ----------------

__global__ void cast_x_kernel(const float* __restrict__ x, short* __restrict__ out, int n4) {
    int i = blockIdx.x * 256 + threadIdx.x;
    if (i < n4) {
        float4 f = ((const float4*)x)[i];
        union { short s[4]; int2 v; } u;
        u.s[0] = f2bf(f.x); u.s[1] = f2bf(f.y); u.s[2] = f2bf(f.z); u.s[3] = f2bf(f.w);
        ((int2*)out)[i] = u.v;
    }
}

// out[n*512 + k] = bf16(W[k*512 + n])
__global__ void transpose_cast_w(const float* __restrict__ W, short* __restrict__ WT) {
    int i = blockIdx.x * 256 + threadIdx.x;   // 0..262143
    int n = i >> 9, k = i & 511;
    WT[i] = f2bf(W[k * 512 + n]);
}

// ---------------- GEMM: C[M,N] = A[M,K] * Bt[N,K]^T (bf16 in, OutT out) ----------------

__device__ inline void store_out(float* p, float v) { *p = v; }
__device__ inline void store_out(short* p, float v) { *p = f2bf(v); }

template <typename OutT>
__global__ __launch_bounds__(256, 2) void gemm_bt(
    const short* __restrict__ A, const short* __restrict__ Bt, OutT* __restrict__ C,
    int M, int N, int Kd)
{
    // pad rows to 40 elems (80B = 16B-mult, not 128B-mult -> ~2-way LDS conflicts)
    __shared__ short sA[64][40];
    __shared__ short sB[64][40];

    const int tid = threadIdx.x;
    const int wv = tid >> 6, lane = tid & 63;
    const int quad = lane >> 4, lr = lane & 15;
    const int m0 = blockIdx.x * 64;
    const int n0 = blockIdx.y * 64;

    f32x4 acc[4];
#pragma unroll
    for (int t = 0; t < 4; ++t) acc[t] = (f32x4){0.f, 0.f, 0.f, 0.f};

    const int srow = tid >> 2;          // 0..63
    const int scol = (tid & 3) * 8;     // 0,8,16,24

    for (int k0 = 0; k0 < Kd; k0 += 32) {
        __syncthreads();
        *(int4*)&sA[srow][scol] = *(const int4*)&A[(m0 + srow) * Kd + k0 + scol];
        *(int4*)&sB[srow][scol] = *(const int4*)&Bt[(n0 + srow) * Kd + k0 + scol];
        __syncthreads();
        bf16x8 a = *(const bf16x8*)&sA[wv * 16 + lr][quad * 8];
#pragma unroll
        for (int t = 0; t < 4; ++t) {
            bf16x8 b = *(const bf16x8*)&sB[t * 16 + lr][quad * 8];
            acc[t] = __builtin_amdgcn_mfma_f32_16x16x32_bf16(a, b, acc[t], 0, 0, 0);
        }
    }

#pragma unroll
    for (int t = 0; t < 4; ++t)
#pragma unroll
        for (int r = 0; r < 4; ++r) {
            int row = m0 + wv * 16 + quad * 4 + r;
            int col = n0 + t * 16 + lr;
            store_out(&C[row * N + col], acc[t][r]);
        }
}

// ---------------- flash-style causal linear attention core ----------------
// Y[b,i,:] = sum_{j<=i} (q_i . k_j) v_j   over rows of one 64-row q-tile.

__global__ __launch_bounds__(256, 1) void flash_causal(
    const short* __restrict__ Q, const short* __restrict__ K, const short* __restrict__ V,
    short* __restrict__ Y)
{
    __shared__ short sQ[64][136];   // 272B rows: 16B-mult, 2-way conflicts
    __shared__ short sK[64][136];
    __shared__ short sP[64][80];    // 160B rows
    __shared__ short sVt[128][104]; // 208B rows; sVt[d][j]

    const int it = blockIdx.x;      // q tile 0..63
    const int b = blockIdx.y;       // batch
    const int tid = threadIdx.x;
    const int wv = tid >> 6, lane = tid & 63;
    const int quad = lane >> 4, lr = lane & 15;

    const int qbase = b * 4096 + it * 64;   // row into [16384][512]

    f32x4 accY[32];
#pragma unroll
    for (int i = 0; i < 32; ++i) accY[i] = (f32x4){0.f, 0.f, 0.f, 0.f};

    for (int jt = 0; jt <= it; ++jt) {
        const int kbase = b * 4096 + jt * 64;

        // ---- S = Q K^T over d, 4 chunks of 128 ----
        f32x4 accS[4];
#pragma unroll
        for (int t = 0; t < 4; ++t) accS[t] = (f32x4){0.f, 0.f, 0.f, 0.f};

        for (int dc = 0; dc < 4; ++dc) {
            __syncthreads();   // protect prior reads of sQ/sK
#pragma unroll
            for (int c = 0; c < 4; ++c) {
                int lin = c * 256 + tid;        // 16B-chunk id 0..1023
                int row = lin >> 4;             // 0..63
                int col = (lin & 15) * 8;       // 0..120
                *(int4*)&sQ[row][col] = *(const int4*)&Q[(qbase + row) * 512 + dc * 128 + col];
                *(int4*)&sK[row][col] = *(const int4*)&K[(kbase + row) * 512 + dc * 128 + col];
            }
            __syncthreads();
#pragma unroll
            for (int kk = 0; kk < 4; ++kk) {
                bf16x8 a = *(const bf16x8*)&sQ[wv * 16 + lr][kk * 32 + quad * 8];
#pragma unroll
                for (int t = 0; t < 4; ++t) {
                    bf16x8 bb = *(const bf16x8*)&sK[t * 16 + lr][kk * 32 + quad * 8];
                    accS[t] = __builtin_amdgcn_mfma_f32_16x16x32_bf16(a, bb, accS[t], 0, 0, 0);
                }
            }
        }

        // ---- mask (diagonal tile) + P -> LDS bf16 ----
        // previous jt's PV phase ended with a barrier, so sP is safe to write
#pragma unroll
        for (int t = 0; t < 4; ++t)
#pragma unroll
            for (int r = 0; r < 4; ++r) {
                int row = wv * 16 + quad * 4 + r;   // query within tile
                int col = t * 16 + lr;              // key within tile
                float s = accS[t][r];
                if (jt == it && col > row) s = 0.f;
                sP[row][col] = f2bf(s);
            }
        __syncthreads();

        // ---- Y += P V, 4 d-out chunks of 128 ----
        for (int dc2 = 0; dc2 < 4; ++dc2) {
#pragma unroll
            for (int cj = 0; cj < 4; ++cj) {
                int j = cj * 16 + (tid >> 4);       // key 0..63
                int dstart = (tid & 15) * 8;        // 0..120
                int4 raw = *(const int4*)&V[(kbase + j) * 512 + dc2 * 128 + dstart];
                short tmp[8];
                *(int4*)tmp = raw;
#pragma unroll
                for (int s = 0; s < 8; ++s) sVt[dstart + s][j] = tmp[s];
            }
            __syncthreads();
#pragma unroll
            for (int kk2 = 0; kk2 < 2; ++kk2) {
                bf16x8 a = *(const bf16x8*)&sP[wv * 16 + lr][kk2 * 32 + quad * 8];
#pragma unroll
                for (int tt = 0; tt < 8; ++tt) {
                    bf16x8 bb = *(const bf16x8*)&sVt[tt * 16 + lr][kk2 * 32 + quad * 8];
                    accY[dc2 * 8 + tt] =
                        __builtin_amdgcn_mfma_f32_16x16x32_bf16(a, bb, accY[dc2 * 8 + tt], 0, 0, 0);
                }
            }
            __syncthreads();   // protect sVt before restage / sP before next jt write
        }
    }

    // ---- epilogue: Y tile -> global bf16 ----
#pragma unroll
    for (int t = 0; t < 32; ++t)
#pragma unroll
        for (int r = 0; r < 4; ++r) {
            int row = wv * 16 + quad * 4 + r;
            int col = t * 16 + lr;
            Y[(qbase + row) * 512 + col] = f2bf(accY[t][r]);
        }
}

// ---------------- host ----------------

extern "C" void kernel_launch(void* const* d_in, const int* in_sizes, int n_in,
                              void* d_out, int out_size, void* d_ws, size_t ws_size,
                              hipStream_t stream) {
    const float* x  = (const float*)d_in[0];
    const float* Wq = (const float*)d_in[1];
    const float* Wk = (const float*)d_in[2];
    const float* Wv = (const float*)d_in[3];
    const float* Wo = (const float*)d_in[4];
    float* out = (float*)d_out;

    const int NT = 16384;   // B*S
    const int D = 512;

    short* ws  = (short*)d_ws;
    short* Xb  = ws;
    short* Qb  = Xb + NT * D;
    short* Kb  = Qb + NT * D;
    short* Vb  = Kb + NT * D;
    short* Yb  = Vb + NT * D;
    short* WqT = Yb + NT * D;
    short* WkT = WqT + D * D;
    short* WvT = WkT + D * D;
    short* WoT = WvT + D * D;

    cast_x_kernel<<<(NT * D / 4 + 255) / 256, 256, 0, stream>>>(x, Xb, NT * D / 4);
    transpose_cast_w<<<1024, 256, 0, stream>>>(Wq, WqT);
    transpose_cast_w<<<1024, 256, 0, stream>>>(Wk, WkT);
    transpose_cast_w<<<1024, 256, 0, stream>>>(Wv, WvT);
    transpose_cast_w<<<1024, 256, 0, stream>>>(Wo, WoT);

    gemm_bt<short><<<dim3(NT / 64, D / 64), 256, 0, stream>>>(Xb, WqT, Qb, NT, D, D);
    gemm_bt<short><<<dim3(NT / 64, D / 64), 256, 0, stream>>>(Xb, WkT, Kb, NT, D, D);
    gemm_bt<short><<<dim3(NT / 64, D / 64), 256, 0, stream>>>(Xb, WvT, Vb, NT, D, D);

    flash_causal<<<dim3(64, 4), 256, 0, stream>>>(Qb, Kb, Vb, Yb);

    gemm_bt<float><<<dim3(NT / 64, D / 64), 256, 0, stream>>>(Yb, WoT, out, NT, D, D);
}

// Round 2
// 261.093 us; speedup vs baseline: 3.8471x; 3.8471x over previous
//
#include <hip/hip_runtime.h>
#include <hip/hip_bf16.h>

typedef __attribute__((ext_vector_type(8))) short bf16x8;
typedef __attribute__((ext_vector_type(4))) float f32x4;

__device__ inline short f2bf(float f) {
    __hip_bfloat16 h = __float2bfloat16(f);
    short s;
    __builtin_memcpy(&s, &h, 2);
    return s;
}
__device__ inline float bf2f(short s) {
    unsigned int u = ((unsigned int)(unsigned short)s) << 16;
    float f;
    __builtin_memcpy(&f, &u, 4);
    return f;
}

// async 16B global -> LDS (dest is wave-uniform base + lane*16; our chunk ids
// are linear in lane, so per-lane `l + c*8` satisfies that)
__device__ inline void cp16_async(const void* g, void* l) {
    __builtin_amdgcn_global_load_lds(
        (const __attribute__((address_space(1))) void*)g,
        (__attribute__((address_space(3))) void*)l, 16, 0, 0);
}

// ---------------- cast / transpose prep ----------------

__global__ void cast_x_kernel(const float* __restrict__ x, short* __restrict__ out, int n4) {
    int i = blockIdx.x * 256 + threadIdx.x;
    if (i < n4) {
        float4 f = ((const float4*)x)[i];
        union { short s[4]; int2 v; } u;
        u.s[0] = f2bf(f.x); u.s[1] = f2bf(f.y); u.s[2] = f2bf(f.z); u.s[3] = f2bf(f.w);
        ((int2*)out)[i] = u.v;
    }
}

// out[n*512 + k] = bf16(W[k*512 + n])
__global__ void transpose_cast_w(const float* __restrict__ W, short* __restrict__ WT) {
    int i = blockIdx.x * 256 + threadIdx.x;
    int n = i >> 9, k = i & 511;
    WT[i] = f2bf(W[k * 512 + n]);
}

// bf16 [4][4096][512] -> [4][512][4096]
__global__ void transpose_bf16(const short* __restrict__ in, short* __restrict__ out) {
    __shared__ short sT[64][72];   // 144B rows: 16B-aligned for b128 reads
    const int t0 = blockIdx.x * 64, f0 = blockIdx.y * 64, b = blockIdx.z;
    const short* ip = in + (size_t)b * 4096 * 512;
    short* op = out + (size_t)b * 512 * 4096;
#pragma unroll
    for (int p = 0; p < 2; ++p) {
        int lin = p * 256 + threadIdx.x;      // 0..511
        int row = lin >> 3, col8 = (lin & 7) * 8;
        short tmp[8];
        *(int4*)tmp = *(const int4*)&ip[(size_t)(t0 + row) * 512 + f0 + col8];
#pragma unroll
        for (int s = 0; s < 8; ++s) sT[col8 + s][row] = tmp[s];
    }
    __syncthreads();
#pragma unroll
    for (int p = 0; p < 2; ++p) {
        int lin = p * 256 + threadIdx.x;
        int fr = lin >> 3, tc8 = (lin & 7) * 8;
        int4 v = *(const int4*)&sT[fr][tc8];
        *(int4*)&op[(size_t)(f0 + fr) * 4096 + t0 + tc8] = v;
    }
}

// ---------------- m97-style 128x128xBK32 MFMA core ----------------
// acc: 16 x f32x4 per thread (wave computes 64x64). A,B are [outer][inner-k]
// tile base pointers; both staged unpadded [128][32] via global_load_lds.

__device__ inline void mfma_tile_kloop(const short* __restrict__ A, int lda,
                                       const short* __restrict__ B, int ldb,
                                       int Kd, f32x4* acc,
                                       short* sA, short* sB) {
    const int tid = threadIdx.x;
    const int lane = tid & 63, wv = tid >> 6;
    const int quad = lane >> 4, lr = lane & 15;
    const int wr = (wv >> 1) * 64, wc = (wv & 1) * 64;
    const int c0 = tid, c1 = tid + 256;
    const int r0 = c0 >> 2, k80 = (c0 & 3) * 8;
    const int r1 = c1 >> 2, k81 = (c1 & 3) * 8;

    for (int k0 = 0; k0 < Kd; k0 += 32) {
        __syncthreads();   // protect prior iter's frag reads
        cp16_async(A + (size_t)r0 * lda + k0 + k80, sA + c0 * 8);
        cp16_async(A + (size_t)r1 * lda + k0 + k81, sA + c1 * 8);
        cp16_async(B + (size_t)r0 * ldb + k0 + k80, sB + c0 * 8);
        cp16_async(B + (size_t)r1 * ldb + k0 + k81, sB + c1 * 8);
        __syncthreads();   // compiler drains vmcnt before barrier
        bf16x8 af[4], bf[4];
#pragma unroll
        for (int i = 0; i < 4; ++i)
            af[i] = *(const bf16x8*)&sA[(wr + i * 16 + lr) * 32 + quad * 8];
#pragma unroll
        for (int j = 0; j < 4; ++j)
            bf[j] = *(const bf16x8*)&sB[(wc + j * 16 + lr) * 32 + quad * 8];
#pragma unroll
        for (int i = 0; i < 4; ++i)
#pragma unroll
            for (int j = 0; j < 4; ++j)
                acc[i * 4 + j] = __builtin_amdgcn_mfma_f32_16x16x32_bf16(af[i], bf[j], acc[i * 4 + j], 0, 0, 0);
    }
}

__device__ inline void store_out(float* p, float v) { *p = v; }
__device__ inline void store_out(short* p, float v) { *p = f2bf(v); }

template <typename OutT>
__device__ inline void store_tile128(OutT* C, int ldc, const f32x4* acc) {
    const int lane = threadIdx.x & 63, wv = threadIdx.x >> 6;
    const int quad = lane >> 4, lr = lane & 15;
    const int wr = (wv >> 1) * 64, wc = (wv & 1) * 64;
#pragma unroll
    for (int i = 0; i < 4; ++i)
#pragma unroll
        for (int j = 0; j < 4; ++j)
#pragma unroll
            for (int r = 0; r < 4; ++r)
                store_out(&C[(size_t)(wr + i * 16 + quad * 4 + r) * ldc + wc + j * 16 + lr],
                          acc[i * 4 + j][r]);
}

// generic C[M,N] = A . Bt^T ; grid (M/128, N/128)
template <typename OutT>
__global__ __launch_bounds__(256, 2) void gemm128(const short* __restrict__ A, int lda,
                                                  const short* __restrict__ B, int ldb,
                                                  OutT* __restrict__ C, int ldc, int Kd) {
    __shared__ short sA[128 * 32], sB[128 * 32];
    const short* At = A + (size_t)blockIdx.x * 128 * lda;
    const short* Bt = B + (size_t)blockIdx.y * 128 * ldb;
    OutT* Ct = C + (size_t)blockIdx.x * 128 * ldc + blockIdx.y * 128;
    f32x4 acc[16];
#pragma unroll
    for (int i = 0; i < 16; ++i) acc[i] = (f32x4){0.f, 0.f, 0.f, 0.f};
    mfma_tile_kloop(At, lda, Bt, ldb, Kd, acc, sA, sB);
    store_tile128(Ct, ldc, acc);
}

// ---------------- chunked linear attention (C=256, 16 chunks/batch) ----------------

// A[b,c][v,k] = sum_{t in chunk} Vt[b][v][t] * Kt[b][k][t]; grid (4,4,64)
__global__ __launch_bounds__(256, 2) void phaseA(const short* __restrict__ Vt,
                                                 const short* __restrict__ Kt,
                                                 short* __restrict__ AM) {
    __shared__ short sA[128 * 32], sB[128 * 32];
    const int bc = blockIdx.z, b = bc >> 4, c = bc & 15;
    const short* Ap = Vt + ((size_t)b * 512 + blockIdx.x * 128) * 4096 + c * 256;
    const short* Bp = Kt + ((size_t)b * 512 + blockIdx.y * 128) * 4096 + c * 256;
    short* Cp = AM + (size_t)bc * 262144 + (size_t)blockIdx.x * 128 * 512 + blockIdx.y * 128;
    f32x4 acc[16];
#pragma unroll
    for (int i = 0; i < 16; ++i) acc[i] = (f32x4){0.f, 0.f, 0.f, 0.f};
    mfma_tile_kloop(Ap, 4096, Bp, 4096, 256, acc, sA, sB);
    store_tile128(Cp, 512, acc);
}

// in-place exclusive prefix over 16 chunks: AM[b][c] := sum_{j<c} AM[b][j]
__global__ void scan_kernel(short* __restrict__ AM) {
    int i = blockIdx.x * 256 + threadIdx.x;   // 0..131071 (4 * 512*512/8)
    int b = i >> 15;
    int vk8 = i & 32767;
    size_t base = (size_t)b * 16 * 262144 + (size_t)vk8 * 8;
    float acc[8];
#pragma unroll
    for (int s = 0; s < 8; ++s) acc[s] = 0.f;
    for (int c = 0; c < 16; ++c) {
        short* p = AM + base + (size_t)c * 262144;
        short in8[8];
        *(int4*)in8 = *(const int4*)p;
        short out8[8];
#pragma unroll
        for (int s = 0; s < 8; ++s) out8[s] = f2bf(acc[s]);
        *(int4*)p = *(const int4*)out8;
#pragma unroll
        for (int s = 0; s < 8; ++s) acc[s] += bf2f(in8[s]);
    }
}

// P[b,c] = tril(Q_c K_c^T) as bf16 [256][256]; grid (2,2,64)
__global__ __launch_bounds__(256, 2) void phaseS(const short* __restrict__ Q,
                                                 const short* __restrict__ K,
                                                 short* __restrict__ P) {
    __shared__ short sA[128 * 32], sB[128 * 32];
    const int bc = blockIdx.z, b = bc >> 4, c = bc & 15;
    const int mt = blockIdx.x, nt = blockIdx.y;
    short* Pt = P + (size_t)bc * 65536 + (size_t)mt * 128 * 256 + nt * 128;
    if (mt < nt) {   // fully-masked tile: zero-fill
        const int4 z = {0, 0, 0, 0};
#pragma unroll
        for (int p = 0; p < 8; ++p) {
            int g = p * 256 + threadIdx.x;          // 0..2047
            int row = g >> 4, c8 = (g & 15) * 8;
            *(int4*)&Pt[(size_t)row * 256 + c8] = z;
        }
        return;
    }
    const short* Ap = Q + ((size_t)(b * 4096 + c * 256 + mt * 128)) * 512;
    const short* Bp = K + ((size_t)(b * 4096 + c * 256 + nt * 128)) * 512;
    f32x4 acc[16];
#pragma unroll
    for (int i = 0; i < 16; ++i) acc[i] = (f32x4){0.f, 0.f, 0.f, 0.f};
    mfma_tile_kloop(Ap, 512, Bp, 512, 512, acc, sA, sB);
    const int lane = threadIdx.x & 63, wv = threadIdx.x >> 6;
    const int quad = lane >> 4, lr = lane & 15;
    const int wr = (wv >> 1) * 64, wc = (wv & 1) * 64;
#pragma unroll
    for (int i = 0; i < 4; ++i)
#pragma unroll
        for (int j = 0; j < 4; ++j)
#pragma unroll
            for (int r = 0; r < 4; ++r) {
                int t = mt * 128 + wr + i * 16 + quad * 4 + r;
                int jj = nt * 128 + wc + j * 16 + lr;
                float v = (jj <= t) ? acc[i * 4 + j][r] : 0.f;
                Pt[(size_t)(wr + i * 16 + quad * 4 + r) * 256 + wc + j * 16 + lr] = f2bf(v);
            }
}

// Y_c = Q_c * Mpre_c^T + P_c * V_c ; grid (2,4,64)
__global__ __launch_bounds__(256, 2) void phaseY(const short* __restrict__ Q,
                                                 const short* __restrict__ Mpre,
                                                 const short* __restrict__ P,
                                                 const short* __restrict__ Vt,
                                                 short* __restrict__ Y) {
    __shared__ short sA[128 * 32], sB[128 * 32];
    const int bc = blockIdx.z, b = bc >> 4, c = bc & 15;
    const int mt = blockIdx.x, nt = blockIdx.y;
    f32x4 acc[16];
#pragma unroll
    for (int i = 0; i < 16; ++i) acc[i] = (f32x4){0.f, 0.f, 0.f, 0.f};
    // inter: Y[t,v] += sum_k Q[t,k] * Mpre[v,k]
    const short* Ai = Q + ((size_t)(b * 4096 + c * 256 + mt * 128)) * 512;
    const short* Bi = Mpre + (size_t)bc * 262144 + (size_t)nt * 128 * 512;
    mfma_tile_kloop(Ai, 512, Bi, 512, 512, acc, sA, sB);
    // intra: Y[t,v] += sum_j P[t,j] * Vt[v,j]
    const short* Ap = P + (size_t)bc * 65536 + (size_t)mt * 128 * 256;
    const short* Bv = Vt + ((size_t)b * 512 + nt * 128) * 4096 + c * 256;
    mfma_tile_kloop(Ap, 256, Bv, 4096, 256, acc, sA, sB);
    short* Cp = Y + ((size_t)(b * 4096 + c * 256 + mt * 128)) * 512 + nt * 128;
    store_tile128(Cp, 512, acc);
}

// ---------------- host ----------------

extern "C" void kernel_launch(void* const* d_in, const int* in_sizes, int n_in,
                              void* d_out, int out_size, void* d_ws, size_t ws_size,
                              hipStream_t stream) {
    const float* x  = (const float*)d_in[0];
    const float* Wq = (const float*)d_in[1];
    const float* Wk = (const float*)d_in[2];
    const float* Wv = (const float*)d_in[3];
    const float* Wo = (const float*)d_in[4];
    float* out = (float*)d_out;

    const size_t NTD = 16384 * 512;   // 8,388,608

    short* ws  = (short*)d_ws;
    short* Qb  = ws;
    short* Kb  = Qb + NTD;
    short* Vb  = Kb + NTD;            // Yb aliases Vb (dead after transpose)
    short* Kt  = Vb + NTD;
    short* Vt  = Kt + NTD;
    short* P   = Vt + NTD;            // 4*16*256*256 = 4,194,304
    short* WqT = P + 4194304;
    short* WkT = WqT + 262144;
    short* WvT = WkT + 262144;
    short* WoT = WvT + 262144;
    short* Xb  = WoT + 262144;        // AM aliases Xb (dead after projections)
    short* AM  = Xb;                  // 4*16*512*512 = 16,777,216 (extends past Xb)
    short* Yb  = Vb;

    cast_x_kernel<<<8192, 256, 0, stream>>>(x, Xb, (int)(NTD / 4));
    transpose_cast_w<<<1024, 256, 0, stream>>>(Wq, WqT);
    transpose_cast_w<<<1024, 256, 0, stream>>>(Wk, WkT);
    transpose_cast_w<<<1024, 256, 0, stream>>>(Wv, WvT);
    transpose_cast_w<<<1024, 256, 0, stream>>>(Wo, WoT);

    // projections: [16384,512] = Xb[16384,512] x W^T
    gemm128<short><<<dim3(128, 4), 256, 0, stream>>>(Xb, 512, WqT, 512, Qb, 512, 512);
    gemm128<short><<<dim3(128, 4), 256, 0, stream>>>(Xb, 512, WkT, 512, Kb, 512, 512);
    gemm128<short><<<dim3(128, 4), 256, 0, stream>>>(Xb, 512, WvT, 512, Vb, 512, 512);

    // feature-major copies for phaseA / PV
    transpose_bf16<<<dim3(64, 8, 4), 256, 0, stream>>>(Kb, Kt);
    transpose_bf16<<<dim3(64, 8, 4), 256, 0, stream>>>(Vb, Vt);

    phaseA<<<dim3(4, 4, 64), 256, 0, stream>>>(Vt, Kt, AM);
    scan_kernel<<<512, 256, 0, stream>>>(AM);
    phaseS<<<dim3(2, 2, 64), 256, 0, stream>>>(Qb, Kb, P);
    phaseY<<<dim3(2, 4, 64), 256, 0, stream>>>(Qb, AM, P, Vt, Yb);

    gemm128<float><<<dim3(128, 4), 256, 0, stream>>>(Yb, 512, WoT, 512, out, 512, 512);
}

// Round 3
// 231.497 us; speedup vs baseline: 4.3390x; 1.1278x over previous
//
#include <hip/hip_runtime.h>
#include <hip/hip_bf16.h>

typedef __attribute__((ext_vector_type(8))) short bf16x8;
typedef __attribute__((ext_vector_type(4))) float f32x4;

__device__ inline short f2bf(float f) {
    __hip_bfloat16 h = __float2bfloat16(f);
    short s;
    __builtin_memcpy(&s, &h, 2);
    return s;
}
__device__ inline float bf2f(short s) {
    unsigned int u = ((unsigned int)(unsigned short)s) << 16;
    float f;
    __builtin_memcpy(&f, &u, 4);
    return f;
}

// async 16B global->LDS; dest must be wave-uniform base + lane*16
__device__ inline void cp16_async(const void* g, void* l) {
    __builtin_amdgcn_global_load_lds(
        (const __attribute__((address_space(1))) void*)g,
        (__attribute__((address_space(3))) void*)l, 16, 0, 0);
}

// ---------------- prep kernels ----------------

__global__ void cast_x_kernel(const float* __restrict__ x, short* __restrict__ out, int n4) {
    int i = blockIdx.x * 256 + threadIdx.x;
    if (i < n4) {
        float4 f = ((const float4*)x)[i];
        union { short s[4]; int2 v; } u;
        u.s[0] = f2bf(f.x); u.s[1] = f2bf(f.y); u.s[2] = f2bf(f.z); u.s[3] = f2bf(f.w);
        ((int2*)out)[i] = u.v;
    }
}

// W4T[w][n][k] = bf16(W_w[k][n]) for the 4 weight matrices
__global__ void transpose_cast_w4(const float* __restrict__ W0, const float* __restrict__ W1,
                                  const float* __restrict__ W2, const float* __restrict__ W3,
                                  short* __restrict__ W4T) {
    int i = blockIdx.x * 256 + threadIdx.x;      // 0 .. 4*262144-1
    int w = i >> 18;
    int r = i & 262143;
    int n = r >> 9, k = r & 511;
    const float* W = (w == 0) ? W0 : (w == 1) ? W1 : (w == 2) ? W2 : W3;
    W4T[i] = f2bf(W[k * 512 + n]);
}

// bf16 [4][4096][512] -> [4][512][4096]
__global__ void transpose_bf16(const short* __restrict__ in, short* __restrict__ out) {
    __shared__ short sT[64][72];
    const int t0 = blockIdx.x * 64, f0 = blockIdx.y * 64, b = blockIdx.z;
    const short* ip = in + (size_t)b * 4096 * 512;
    short* op = out + (size_t)b * 512 * 4096;
#pragma unroll
    for (int p = 0; p < 2; ++p) {
        int lin = p * 256 + threadIdx.x;
        int row = lin >> 3, col8 = (lin & 7) * 8;
        short tmp[8];
        *(int4*)tmp = *(const int4*)&ip[(size_t)(t0 + row) * 512 + f0 + col8];
#pragma unroll
        for (int s = 0; s < 8; ++s) sT[col8 + s][row] = tmp[s];
    }
    __syncthreads();
#pragma unroll
    for (int p = 0; p < 2; ++p) {
        int lin = p * 256 + threadIdx.x;
        int fr = lin >> 3, tc8 = (lin & 7) * 8;
        int4 v = *(const int4*)&sT[fr][tc8];
        *(int4*)&op[(size_t)(f0 + fr) * 4096 + t0 + tc8] = v;
    }
}

// ---------------- 128x128 MFMA core, K-step 64 via 4 m97-style panels ----------------

#define LDS_DECL __shared__ short sA0[4096], sA1[4096], sB0[4096], sB1[4096]

__device__ inline void mfma_kloop64(const short* __restrict__ A, int lda,
                                    const short* __restrict__ B, int ldb,
                                    int Kd, f32x4* acc,
                                    short* sA0, short* sA1, short* sB0, short* sB1) {
    const int tid = threadIdx.x, lane = tid & 63, wv = tid >> 6;
    const int quad = lane >> 4, lr = lane & 15;
    const int wr = (wv >> 1) * 64, wc = (wv & 1) * 64;
    const int c0 = tid, c1 = tid + 256;
    const int r0 = c0 >> 2, k80 = (c0 & 3) * 8;
    const int r1 = c1 >> 2, k81 = (c1 & 3) * 8;

    for (int k0 = 0; k0 < Kd; k0 += 64) {
        __syncthreads();   // protect prior iter's fragment reads
        cp16_async(A + (size_t)r0 * lda + k0 + k80,      sA0 + c0 * 8);
        cp16_async(A + (size_t)r1 * lda + k0 + k81,      sA0 + c1 * 8);
        cp16_async(A + (size_t)r0 * lda + k0 + 32 + k80, sA1 + c0 * 8);
        cp16_async(A + (size_t)r1 * lda + k0 + 32 + k81, sA1 + c1 * 8);
        cp16_async(B + (size_t)r0 * ldb + k0 + k80,      sB0 + c0 * 8);
        cp16_async(B + (size_t)r1 * ldb + k0 + k81,      sB0 + c1 * 8);
        cp16_async(B + (size_t)r0 * ldb + k0 + 32 + k80, sB1 + c0 * 8);
        cp16_async(B + (size_t)r1 * ldb + k0 + 32 + k81, sB1 + c1 * 8);
        __syncthreads();   // compiler drains vmcnt(0) here
#pragma unroll
        for (int half = 0; half < 2; ++half) {
            const short* pa = half ? sA1 : sA0;
            const short* pb = half ? sB1 : sB0;
            bf16x8 af[4], bfr[4];
#pragma unroll
            for (int i = 0; i < 4; ++i)
                af[i] = *(const bf16x8*)&pa[(wr + i * 16 + lr) * 32 + quad * 8];
#pragma unroll
            for (int j = 0; j < 4; ++j)
                bfr[j] = *(const bf16x8*)&pb[(wc + j * 16 + lr) * 32 + quad * 8];
#pragma unroll
            for (int i = 0; i < 4; ++i)
#pragma unroll
                for (int j = 0; j < 4; ++j)
                    acc[i * 4 + j] = __builtin_amdgcn_mfma_f32_16x16x32_bf16(af[i], bfr[j], acc[i * 4 + j], 0, 0, 0);
        }
    }
}

__device__ inline void store_out(float* p, float v) { *p = v; }
__device__ inline void store_out(short* p, float v) { *p = f2bf(v); }

template <typename OutT>
__device__ inline void store_tile128(OutT* C, int ldc, const f32x4* acc) {
    const int lane = threadIdx.x & 63, wv = threadIdx.x >> 6;
    const int quad = lane >> 4, lr = lane & 15;
    const int wr = (wv >> 1) * 64, wc = (wv & 1) * 64;
#pragma unroll
    for (int i = 0; i < 4; ++i)
#pragma unroll
        for (int j = 0; j < 4; ++j)
#pragma unroll
            for (int r = 0; r < 4; ++r)
                store_out(&C[(size_t)(wr + i * 16 + quad * 4 + r) * ldc + wc + j * 16 + lr],
                          acc[i * 4 + j][r]);
}

// ---------------- projection kernels ----------------

// fused Q/K projection: grid (128, 8); by<4 -> Q cols, else K cols
__global__ __launch_bounds__(256, 2) void gemm_qk(const short* __restrict__ Xb,
                                                  const short* __restrict__ WqkT,
                                                  short* __restrict__ Qb, short* __restrict__ Kb) {
    LDS_DECL;
    const short* At = Xb + (size_t)blockIdx.x * 128 * 512;
    const short* Bt = WqkT + (size_t)blockIdx.y * 128 * 512;
    short* Cbase = (blockIdx.y < 4) ? Qb : Kb;
    int n0 = (blockIdx.y & 3) * 128;
    short* Ct = Cbase + (size_t)blockIdx.x * 128 * 512 + n0;
    f32x4 acc[16];
#pragma unroll
    for (int i = 0; i < 16; ++i) acc[i] = (f32x4){0.f, 0.f, 0.f, 0.f};
    mfma_kloop64(At, 512, Bt, 512, 512, acc, sA0, sA1, sB0, sB1);
    store_tile128(Ct, 512, acc);
}

// direct feature-major V: Vt[b][f][t] = sum_d WvT[f][d] * Xb[b*4096+t][d]
// grid (4 f-tiles, 32 t-tiles, 4 batches)
__global__ __launch_bounds__(256, 2) void gemm_vt(const short* __restrict__ WvT,
                                                  const short* __restrict__ Xb,
                                                  short* __restrict__ Vt) {
    LDS_DECL;
    const int b = blockIdx.z;
    const short* At = WvT + (size_t)blockIdx.x * 128 * 512;
    const short* Bt = Xb + ((size_t)b * 4096 + blockIdx.y * 128) * 512;
    short* Ct = Vt + (size_t)b * 512 * 4096 + (size_t)blockIdx.x * 128 * 4096 + blockIdx.y * 128;
    f32x4 acc[16];
#pragma unroll
    for (int i = 0; i < 16; ++i) acc[i] = (f32x4){0.f, 0.f, 0.f, 0.f};
    mfma_kloop64(At, 512, Bt, 512, 512, acc, sA0, sA1, sB0, sB1);
    store_tile128(Ct, 4096, acc);
}

// generic C[M,N] = A . Bt^T (used for output projection)
template <typename OutT>
__global__ __launch_bounds__(256, 2) void gemm128(const short* __restrict__ A, int lda,
                                                  const short* __restrict__ B, int ldb,
                                                  OutT* __restrict__ C, int ldc, int Kd) {
    LDS_DECL;
    const short* At = A + (size_t)blockIdx.x * 128 * lda;
    const short* Bt = B + (size_t)blockIdx.y * 128 * ldb;
    OutT* Ct = C + (size_t)blockIdx.x * 128 * ldc + blockIdx.y * 128;
    f32x4 acc[16];
#pragma unroll
    for (int i = 0; i < 16; ++i) acc[i] = (f32x4){0.f, 0.f, 0.f, 0.f};
    mfma_kloop64(At, lda, Bt, ldb, Kd, acc, sA0, sA1, sB0, sB1);
    store_tile128(Ct, ldc, acc);
}

// ---------------- chunked linear attention (C=256, 16 chunks/batch) ----------------

// AM[b,c][v][k] = sum_{t in chunk c} Vt[b][v][t] * Kt[b][k][t]; grid (4,4,64)
__global__ __launch_bounds__(256, 2) void phaseA(const short* __restrict__ Vt,
                                                 const short* __restrict__ Kt,
                                                 short* __restrict__ AM) {
    LDS_DECL;
    const int bc = blockIdx.z, b = bc >> 4, c = bc & 15;
    const short* Ap = Vt + ((size_t)b * 512 + blockIdx.x * 128) * 4096 + c * 256;
    const short* Bp = Kt + ((size_t)b * 512 + blockIdx.y * 128) * 4096 + c * 256;
    short* Cp = AM + (size_t)bc * 262144 + (size_t)blockIdx.x * 128 * 512 + blockIdx.y * 128;
    f32x4 acc[16];
#pragma unroll
    for (int i = 0; i < 16; ++i) acc[i] = (f32x4){0.f, 0.f, 0.f, 0.f};
    mfma_kloop64(Ap, 4096, Bp, 4096, 256, acc, sA0, sA1, sB0, sB1);
    store_tile128(Cp, 512, acc);
}

// in-place exclusive prefix over 16 chunks
__global__ void scan_kernel(short* __restrict__ AM) {
    int i = blockIdx.x * 256 + threadIdx.x;   // 0..131071
    int b = i >> 15;
    int vk8 = i & 32767;
    size_t base = (size_t)b * 16 * 262144 + (size_t)vk8 * 8;
    float acc[8];
#pragma unroll
    for (int s = 0; s < 8; ++s) acc[s] = 0.f;
    for (int c = 0; c < 16; ++c) {
        short* p = AM + base + (size_t)c * 262144;
        short in8[8];
        *(int4*)in8 = *(const int4*)p;
        short out8[8];
#pragma unroll
        for (int s = 0; s < 8; ++s) out8[s] = f2bf(acc[s]);
        *(int4*)p = *(const int4*)out8;
#pragma unroll
        for (int s = 0; s < 8; ++s) acc[s] += bf2f(in8[s]);
    }
}

// P[b,c] = tril(Q_c K_c^T) bf16 [256][256]; grid (2,2,64); tile (0,1) never read
__global__ __launch_bounds__(256, 2) void phaseS(const short* __restrict__ Q,
                                                 const short* __restrict__ K,
                                                 short* __restrict__ P) {
    LDS_DECL;
    const int bc = blockIdx.z, b = bc >> 4, c = bc & 15;
    const int mt = blockIdx.x, nt = blockIdx.y;
    if (mt < nt) return;   // dead tile (phaseY never reads it)
    short* Pt = P + (size_t)bc * 65536 + (size_t)mt * 128 * 256 + nt * 128;
    const short* Ap = Q + ((size_t)(b * 4096 + c * 256 + mt * 128)) * 512;
    const short* Bp = K + ((size_t)(b * 4096 + c * 256 + nt * 128)) * 512;
    f32x4 acc[16];
#pragma unroll
    for (int i = 0; i < 16; ++i) acc[i] = (f32x4){0.f, 0.f, 0.f, 0.f};
    mfma_kloop64(Ap, 512, Bp, 512, 512, acc, sA0, sA1, sB0, sB1);
    const int lane = threadIdx.x & 63, wv = threadIdx.x >> 6;
    const int quad = lane >> 4, lr = lane & 15;
    const int wr = (wv >> 1) * 64, wc = (wv & 1) * 64;
    const bool diag = (mt == nt);
#pragma unroll
    for (int i = 0; i < 4; ++i)
#pragma unroll
        for (int j = 0; j < 4; ++j)
#pragma unroll
            for (int r = 0; r < 4; ++r) {
                int t = wr + i * 16 + quad * 4 + r;
                int jj = wc + j * 16 + lr;
                float v = (!diag || jj <= t) ? acc[i * 4 + j][r] : 0.f;
                Pt[(size_t)t * 256 + jj] = f2bf(v);
            }
}

// Y_c = Q_c * Mpre_c^T + tril(P_c) * V_c ; grid (2 mt, 4 nt, 64 bc)
__global__ __launch_bounds__(256, 2) void phaseY(const short* __restrict__ Q,
                                                 const short* __restrict__ Mpre,
                                                 const short* __restrict__ P,
                                                 const short* __restrict__ Vt,
                                                 short* __restrict__ Y) {
    LDS_DECL;
    const int bc = blockIdx.z, b = bc >> 4, c = bc & 15;
    const int mt = blockIdx.x, nt = blockIdx.y;
    f32x4 acc[16];
#pragma unroll
    for (int i = 0; i < 16; ++i) acc[i] = (f32x4){0.f, 0.f, 0.f, 0.f};
    // inter: Y[t][v] += sum_k Q[t][k] * Mpre[v][k]
    const short* Ai = Q + ((size_t)(b * 4096 + c * 256 + mt * 128)) * 512;
    const short* Bi = Mpre + (size_t)bc * 262144 + (size_t)nt * 128 * 512;
    mfma_kloop64(Ai, 512, Bi, 512, 512, acc, sA0, sA1, sB0, sB1);
    // intra: Y[t][v] += sum_{j<=...} P[t][j] * Vt[v][j]; for mt=0 only j<128 nonzero
    const short* Ap = P + (size_t)bc * 65536 + (size_t)mt * 128 * 256;
    const short* Bv = Vt + ((size_t)b * 512 + nt * 128) * 4096 + c * 256;
    mfma_kloop64(Ap, 256, Bv, 4096, (mt + 1) * 128, acc, sA0, sA1, sB0, sB1);
    short* Cp = Y + ((size_t)(b * 4096 + c * 256 + mt * 128)) * 512 + nt * 128;
    store_tile128(Cp, 512, acc);
}

// ---------------- host ----------------

extern "C" void kernel_launch(void* const* d_in, const int* in_sizes, int n_in,
                              void* d_out, int out_size, void* d_ws, size_t ws_size,
                              hipStream_t stream) {
    const float* x  = (const float*)d_in[0];
    const float* Wq = (const float*)d_in[1];
    const float* Wk = (const float*)d_in[2];
    const float* Wv = (const float*)d_in[3];
    const float* Wo = (const float*)d_in[4];
    float* out = (float*)d_out;

    const size_t NTD = 16384 * 512;   // 8,388,608 elems

    short* ws  = (short*)d_ws;
    short* Xb  = ws;                  // 8.39M
    short* Qb  = Xb + NTD;
    short* Kb  = Qb + NTD;
    short* Kt  = Kb + NTD;
    short* Vt  = Kt + NTD;
    short* P   = Vt + NTD;            // 4.19M
    short* W4T = P + 4194304;         // 1.05M : WqT|WkT|WvT|WoT
    short* AM  = W4T + 1048576;       // 16.78M
    short* Yb  = Kb;                  // Kb dead after phaseS

    short* WqT = W4T;
    short* WvT = W4T + 2 * 262144;
    short* WoT = W4T + 3 * 262144;

    cast_x_kernel<<<8192, 256, 0, stream>>>(x, Xb, (int)(NTD / 4));
    transpose_cast_w4<<<4096, 256, 0, stream>>>(Wq, Wk, Wv, Wo, W4T);

    gemm_qk<<<dim3(128, 8), 256, 0, stream>>>(Xb, WqT, Qb, Kb);
    gemm_vt<<<dim3(4, 32, 4), 256, 0, stream>>>(WvT, Xb, Vt);
    transpose_bf16<<<dim3(64, 8, 4), 256, 0, stream>>>(Kb, Kt);

    phaseA<<<dim3(4, 4, 64), 256, 0, stream>>>(Vt, Kt, AM);
    scan_kernel<<<512, 256, 0, stream>>>(AM);
    phaseS<<<dim3(2, 2, 64), 256, 0, stream>>>(Qb, Kb, P);
    phaseY<<<dim3(2, 4, 64), 256, 0, stream>>>(Qb, AM, P, Vt, Yb);

    gemm128<float><<<dim3(128, 4), 256, 0, stream>>>(Yb, 512, WoT, 512, out, 512, 512);
}

// Round 4
// 222.161 us; speedup vs baseline: 4.5213x; 1.0420x over previous
//
#include <hip/hip_runtime.h>
#include <hip/hip_bf16.h>

typedef __attribute__((ext_vector_type(8))) short bf16x8;
typedef __attribute__((ext_vector_type(4))) float f32x4;

__device__ inline short f2bf(float f) {
    __hip_bfloat16 h = __float2bfloat16(f);
    short s;
    __builtin_memcpy(&s, &h, 2);
    return s;
}
__device__ inline float bf2f(short s) {
    unsigned int u = ((unsigned int)(unsigned short)s) << 16;
    float f;
    __builtin_memcpy(&f, &u, 4);
    return f;
}

// async 16B global->LDS; dest must be wave-uniform base + lane*16
__device__ inline void cp16_async(const void* g, void* l) {
    __builtin_amdgcn_global_load_lds(
        (const __attribute__((address_space(1))) void*)g,
        (__attribute__((address_space(3))) void*)l, 16, 0, 0);
}

// ---------------- prep: cast x + transpose-cast all 4 weights ----------------

__global__ void prep_kernel(const float* __restrict__ x, short* __restrict__ Xb,
                            const float* __restrict__ W0, const float* __restrict__ W1,
                            const float* __restrict__ W2, const float* __restrict__ W3,
                            short* __restrict__ W4T) {
    int bid = blockIdx.x;
    if (bid < 8192) {
        int i = bid * 256 + threadIdx.x;          // < 2,097,152 float4s
        float4 f = ((const float4*)x)[i];
        union { short s[4]; int2 v; } u;
        u.s[0] = f2bf(f.x); u.s[1] = f2bf(f.y); u.s[2] = f2bf(f.z); u.s[3] = f2bf(f.w);
        ((int2*)Xb)[i] = u.v;
    } else {
        int i = (bid - 8192) * 256 + threadIdx.x; // 0 .. 4*262144-1
        int w = i >> 18;
        int r = i & 262143;
        int n = r >> 9, k = r & 511;
        const float* W = (w == 0) ? W0 : (w == 1) ? W1 : (w == 2) ? W2 : W3;
        W4T[i] = f2bf(W[k * 512 + n]);
    }
}

// ---------------- 128x128 MFMA core, K-step 64 via 4 m97-style panels ----------------

#define LDS_DECL __shared__ short sA0[4096], sA1[4096], sB0[4096], sB1[4096]

__device__ inline void mfma_kloop64(const short* __restrict__ A, int lda,
                                    const short* __restrict__ B, int ldb,
                                    int Kd, f32x4* acc,
                                    short* sA0, short* sA1, short* sB0, short* sB1) {
    const int tid = threadIdx.x, lane = tid & 63, wv = tid >> 6;
    const int quad = lane >> 4, lr = lane & 15;
    const int wr = (wv >> 1) * 64, wc = (wv & 1) * 64;
    const int c0 = tid, c1 = tid + 256;
    const int r0 = c0 >> 2, k80 = (c0 & 3) * 8;
    const int r1 = c1 >> 2, k81 = (c1 & 3) * 8;

    for (int k0 = 0; k0 < Kd; k0 += 64) {
        __syncthreads();   // protect prior iter's fragment reads
        cp16_async(A + (size_t)r0 * lda + k0 + k80,      sA0 + c0 * 8);
        cp16_async(A + (size_t)r1 * lda + k0 + k81,      sA0 + c1 * 8);
        cp16_async(A + (size_t)r0 * lda + k0 + 32 + k80, sA1 + c0 * 8);
        cp16_async(A + (size_t)r1 * lda + k0 + 32 + k81, sA1 + c1 * 8);
        cp16_async(B + (size_t)r0 * ldb + k0 + k80,      sB0 + c0 * 8);
        cp16_async(B + (size_t)r1 * ldb + k0 + k81,      sB0 + c1 * 8);
        cp16_async(B + (size_t)r0 * ldb + k0 + 32 + k80, sB1 + c0 * 8);
        cp16_async(B + (size_t)r1 * ldb + k0 + 32 + k81, sB1 + c1 * 8);
        __syncthreads();   // compiler drains vmcnt(0) here
#pragma unroll
        for (int half = 0; half < 2; ++half) {
            const short* pa = half ? sA1 : sA0;
            const short* pb = half ? sB1 : sB0;
            bf16x8 af[4], bfr[4];
#pragma unroll
            for (int i = 0; i < 4; ++i)
                af[i] = *(const bf16x8*)&pa[(wr + i * 16 + lr) * 32 + quad * 8];
#pragma unroll
            for (int j = 0; j < 4; ++j)
                bfr[j] = *(const bf16x8*)&pb[(wc + j * 16 + lr) * 32 + quad * 8];
#pragma unroll
            for (int i = 0; i < 4; ++i)
#pragma unroll
                for (int j = 0; j < 4; ++j)
                    acc[i * 4 + j] = __builtin_amdgcn_mfma_f32_16x16x32_bf16(af[i], bfr[j], acc[i * 4 + j], 0, 0, 0);
        }
    }
}

__device__ inline void store_out(float* p, float v) { *p = v; }
__device__ inline void store_out(short* p, float v) { *p = f2bf(v); }

template <typename OutT>
__device__ inline void store_tile128(OutT* C, int ldc, const f32x4* acc) {
    const int lane = threadIdx.x & 63, wv = threadIdx.x >> 6;
    const int quad = lane >> 4, lr = lane & 15;
    const int wr = (wv >> 1) * 64, wc = (wv & 1) * 64;
#pragma unroll
    for (int i = 0; i < 4; ++i)
#pragma unroll
        for (int j = 0; j < 4; ++j)
#pragma unroll
            for (int r = 0; r < 4; ++r)
                store_out(&C[(size_t)(wr + i * 16 + quad * 4 + r) * ldc + wc + j * 16 + lr],
                          acc[i * 4 + j][r]);
}

// ---------------- unified projections: Qb, Kb (row-major), Vt, Kt (feature-major) ----------------
// grid 2048 blocks:
//   0..1023   : Qb|Kb: mt = bid>>3 (0..127), by = bid&7 (<4 -> Q cols, else K cols)
//   1024..2047: Vt|Kt: which = (bid-1024)>>9; r = (bid-1024)&511 -> b = r&3, tt = (r>>2)&31, ft = r>>7
__global__ __launch_bounds__(256, 2) void proj_all(const short* __restrict__ Xb,
                                                   const short* __restrict__ W4T,
                                                   short* __restrict__ Qb, short* __restrict__ Kb,
                                                   short* __restrict__ Vt, short* __restrict__ Kt) {
    LDS_DECL;
    f32x4 acc[16];
#pragma unroll
    for (int i = 0; i < 16; ++i) acc[i] = (f32x4){0.f, 0.f, 0.f, 0.f};
    const int bid = blockIdx.x;
    if (bid < 1024) {
        const int mt = bid >> 3, by = bid & 7;
        const short* At = Xb + (size_t)mt * 128 * 512;
        const short* Bt = W4T + (size_t)by * 128 * 512;   // by<4: Wq, else Wk
        short* Ct = ((by < 4) ? Qb : Kb) + (size_t)mt * 128 * 512 + (by & 3) * 128;
        mfma_kloop64(At, 512, Bt, 512, 512, acc, sA0, sA1, sB0, sB1);
        store_tile128(Ct, 512, acc);
    } else {
        const int g = bid - 1024;
        const int which = g >> 9;           // 0 -> Vt (Wv), 1 -> Kt (Wk)
        const int r = g & 511;
        const int b = r & 3, tt = (r >> 2) & 31, ft = r >> 7;
        const short* At = W4T + (size_t)(which ? 1 : 2) * 262144 + (size_t)ft * 128 * 512;
        const short* Bt = Xb + ((size_t)b * 4096 + tt * 128) * 512;
        short* Ct = (which ? Kt : Vt) + (size_t)b * 512 * 4096 + (size_t)ft * 128 * 4096 + tt * 128;
        mfma_kloop64(At, 512, Bt, 512, 512, acc, sA0, sA1, sB0, sB1);
        store_tile128(Ct, 4096, acc);
    }
}

// ---------------- chunked linear attention (C=256, 16 chunks/batch) ----------------

// AM[b,c][v][k] = sum_{t in chunk c} Vt[b][v][t] * Kt[b][k][t]; grid (4,4,64)
__global__ __launch_bounds__(256, 2) void phaseA(const short* __restrict__ Vt,
                                                 const short* __restrict__ Kt,
                                                 short* __restrict__ AM) {
    LDS_DECL;
    const int bc = blockIdx.z, b = bc >> 4, c = bc & 15;
    const short* Ap = Vt + ((size_t)b * 512 + blockIdx.x * 128) * 4096 + c * 256;
    const short* Bp = Kt + ((size_t)b * 512 + blockIdx.y * 128) * 4096 + c * 256;
    short* Cp = AM + (size_t)bc * 262144 + (size_t)blockIdx.x * 128 * 512 + blockIdx.y * 128;
    f32x4 acc[16];
#pragma unroll
    for (int i = 0; i < 16; ++i) acc[i] = (f32x4){0.f, 0.f, 0.f, 0.f};
    mfma_kloop64(Ap, 4096, Bp, 4096, 256, acc, sA0, sA1, sB0, sB1);
    store_tile128(Cp, 512, acc);
}

// merged: blocks 0..511 = exclusive prefix scan over chunks of AM (memory-bound);
//         blocks 512..767 = P = tril(Q_c K_c^T) (compute-bound) -- independent, overlap.
__global__ __launch_bounds__(256, 2) void scan_phaseS(short* __restrict__ AM,
                                                      const short* __restrict__ Q,
                                                      const short* __restrict__ K,
                                                      short* __restrict__ P) {
    LDS_DECL;
    if (blockIdx.x < 512) {
        int i = blockIdx.x * 256 + threadIdx.x;   // 0..131071
        int b = i >> 15;
        int vk8 = i & 32767;
        size_t base = (size_t)b * 16 * 262144 + (size_t)vk8 * 8;
        float acc[8];
#pragma unroll
        for (int s = 0; s < 8; ++s) acc[s] = 0.f;
        for (int c = 0; c < 16; ++c) {
            short* p = AM + base + (size_t)c * 262144;
            short in8[8];
            *(int4*)in8 = *(const int4*)p;
            short out8[8];
#pragma unroll
            for (int s = 0; s < 8; ++s) out8[s] = f2bf(acc[s]);
            *(int4*)p = *(const int4*)out8;
#pragma unroll
            for (int s = 0; s < 8; ++s) acc[s] += bf2f(in8[s]);
        }
        return;
    }
    const int e = blockIdx.x - 512;               // 0..255
    const int bc = e >> 2, mt = e & 1, nt = (e >> 1) & 1;
    if (mt < nt) return;                          // dead tile (never read)
    const int b = bc >> 4, c = bc & 15;
    short* Pt = P + (size_t)bc * 65536 + (size_t)mt * 128 * 256 + nt * 128;
    const short* Ap = Q + ((size_t)(b * 4096 + c * 256 + mt * 128)) * 512;
    const short* Bp = K + ((size_t)(b * 4096 + c * 256 + nt * 128)) * 512;
    f32x4 acc[16];
#pragma unroll
    for (int i = 0; i < 16; ++i) acc[i] = (f32x4){0.f, 0.f, 0.f, 0.f};
    mfma_kloop64(Ap, 512, Bp, 512, 512, acc, sA0, sA1, sB0, sB1);
    const int lane = threadIdx.x & 63, wv = threadIdx.x >> 6;
    const int quad = lane >> 4, lr = lane & 15;
    const int wr = (wv >> 1) * 64, wc = (wv & 1) * 64;
    const bool diag = (mt == nt);
#pragma unroll
    for (int i = 0; i < 4; ++i)
#pragma unroll
        for (int j = 0; j < 4; ++j)
#pragma unroll
            for (int r = 0; r < 4; ++r) {
                int t = wr + i * 16 + quad * 4 + r;
                int jj = wc + j * 16 + lr;
                float v = (!diag || jj <= t) ? acc[i * 4 + j][r] : 0.f;
                Pt[(size_t)t * 256 + jj] = f2bf(v);
            }
}

// Y_c = Q_c * Mpre_c^T + tril(P_c) * V_c ; grid (2 mt, 4 nt, 64 bc)
__global__ __launch_bounds__(256, 2) void phaseY(const short* __restrict__ Q,
                                                 const short* __restrict__ Mpre,
                                                 const short* __restrict__ P,
                                                 const short* __restrict__ Vt,
                                                 short* __restrict__ Y) {
    LDS_DECL;
    const int bc = blockIdx.z, b = bc >> 4, c = bc & 15;
    const int mt = blockIdx.x, nt = blockIdx.y;
    f32x4 acc[16];
#pragma unroll
    for (int i = 0; i < 16; ++i) acc[i] = (f32x4){0.f, 0.f, 0.f, 0.f};
    // inter: Y[t][v] += sum_k Q[t][k] * Mpre[v][k]
    const short* Ai = Q + ((size_t)(b * 4096 + c * 256 + mt * 128)) * 512;
    const short* Bi = Mpre + (size_t)bc * 262144 + (size_t)nt * 128 * 512;
    mfma_kloop64(Ai, 512, Bi, 512, 512, acc, sA0, sA1, sB0, sB1);
    // intra: Y[t][v] += sum_j P[t][j] * Vt[v][j]; for mt=0 only j<128 nonzero
    const short* Ap = P + (size_t)bc * 65536 + (size_t)mt * 128 * 256;
    const short* Bv = Vt + ((size_t)b * 512 + nt * 128) * 4096 + c * 256;
    mfma_kloop64(Ap, 256, Bv, 4096, (mt + 1) * 128, acc, sA0, sA1, sB0, sB1);
    short* Cp = Y + ((size_t)(b * 4096 + c * 256 + mt * 128)) * 512 + nt * 128;
    store_tile128(Cp, 512, acc);
}

// generic C[M,N] = A . Bt^T (output projection)
template <typename OutT>
__global__ __launch_bounds__(256, 2) void gemm128(const short* __restrict__ A, int lda,
                                                  const short* __restrict__ B, int ldb,
                                                  OutT* __restrict__ C, int ldc, int Kd) {
    LDS_DECL;
    const short* At = A + (size_t)blockIdx.x * 128 * lda;
    const short* Bt = B + (size_t)blockIdx.y * 128 * ldb;
    OutT* Ct = C + (size_t)blockIdx.x * 128 * ldc + blockIdx.y * 128;
    f32x4 acc[16];
#pragma unroll
    for (int i = 0; i < 16; ++i) acc[i] = (f32x4){0.f, 0.f, 0.f, 0.f};
    mfma_kloop64(At, lda, Bt, ldb, Kd, acc, sA0, sA1, sB0, sB1);
    store_tile128(Ct, ldc, acc);
}

// ---------------- host ----------------

extern "C" void kernel_launch(void* const* d_in, const int* in_sizes, int n_in,
                              void* d_out, int out_size, void* d_ws, size_t ws_size,
                              hipStream_t stream) {
    const float* x  = (const float*)d_in[0];
    const float* Wq = (const float*)d_in[1];
    const float* Wk = (const float*)d_in[2];
    const float* Wv = (const float*)d_in[3];
    const float* Wo = (const float*)d_in[4];
    float* out = (float*)d_out;

    const size_t NTD = 16384 * 512;   // 8,388,608 elems

    short* ws  = (short*)d_ws;
    short* Xb  = ws;                  // 8.39M
    short* Qb  = Xb + NTD;
    short* Kb  = Qb + NTD;
    short* Kt  = Kb + NTD;
    short* Vt  = Kt + NTD;
    short* P   = Vt + NTD;            // 4.19M
    short* W4T = P + 4194304;         // 1.05M : WqT|WkT|WvT|WoT
    short* AM  = W4T + 1048576;       // 16.78M
    short* Yb  = Kb;                  // Kb dead after scan_phaseS

    short* WoT = W4T + 3 * 262144;

    prep_kernel<<<12288, 256, 0, stream>>>(x, Xb, Wq, Wk, Wv, Wo, W4T);
    proj_all<<<2048, 256, 0, stream>>>(Xb, W4T, Qb, Kb, Vt, Kt);
    phaseA<<<dim3(4, 4, 64), 256, 0, stream>>>(Vt, Kt, AM);
    scan_phaseS<<<768, 256, 0, stream>>>(AM, Qb, Kb, P);
    phaseY<<<dim3(2, 4, 64), 256, 0, stream>>>(Qb, AM, P, Vt, Yb);
    gemm128<float><<<dim3(128, 4), 256, 0, stream>>>(Yb, 512, WoT, 512, out, 512, 512);
}

// Round 5
// 222.048 us; speedup vs baseline: 4.5236x; 1.0005x over previous
//
#include <hip/hip_runtime.h>
#include <hip/hip_bf16.h>

typedef __attribute__((ext_vector_type(8))) short bf16x8;
typedef __attribute__((ext_vector_type(4))) float f32x4;

__device__ inline short f2bf(float f) {
    __hip_bfloat16 h = __float2bfloat16(f);
    short s;
    __builtin_memcpy(&s, &h, 2);
    return s;
}
__device__ inline float bf2f(short s) {
    unsigned int u = ((unsigned int)(unsigned short)s) << 16;
    float f;
    __builtin_memcpy(&f, &u, 4);
    return f;
}

// async 16B global->LDS; dest must be wave-uniform base + lane*16
__device__ inline void cp16_async(const void* g, void* l) {
    __builtin_amdgcn_global_load_lds(
        (const __attribute__((address_space(1))) void*)g,
        (__attribute__((address_space(3))) void*)l, 16, 0, 0);
}

// ---------------- prep: cast x + transpose-cast all 4 weights ----------------

__global__ void prep_kernel(const float* __restrict__ x, short* __restrict__ Xb,
                            const float* __restrict__ W0, const float* __restrict__ W1,
                            const float* __restrict__ W2, const float* __restrict__ W3,
                            short* __restrict__ W4T) {
    int bid = blockIdx.x;
    if (bid < 8192) {
        int i = bid * 256 + threadIdx.x;
        float4 f = ((const float4*)x)[i];
        union { short s[4]; int2 v; } u;
        u.s[0] = f2bf(f.x); u.s[1] = f2bf(f.y); u.s[2] = f2bf(f.z); u.s[3] = f2bf(f.w);
        ((int2*)Xb)[i] = u.v;
    } else {
        int i = (bid - 8192) * 256 + threadIdx.x;
        int w = i >> 18;
        int r = i & 262143;
        int n = r >> 9, k = r & 511;
        const float* W = (w == 0) ? W0 : (w == 1) ? W1 : (w == 2) ? W2 : W3;
        W4T[i] = f2bf(W[k * 512 + n]);
    }
}

// ---------------- 128x128 MFMA core, K-step 64 via 4 m97-style panels ----------------

#define LDS_DECL __shared__ short sA0[4096], sA1[4096], sB0[4096], sB1[4096]

__device__ inline void mfma_kloop64(const short* __restrict__ A, int lda,
                                    const short* __restrict__ B, int ldb,
                                    int Kd, f32x4* acc,
                                    short* sA0, short* sA1, short* sB0, short* sB1) {
    const int tid = threadIdx.x, lane = tid & 63, wv = tid >> 6;
    const int quad = lane >> 4, lr = lane & 15;
    const int wr = (wv >> 1) * 64, wc = (wv & 1) * 64;
    const int c0 = tid, c1 = tid + 256;
    const int r0 = c0 >> 2, k80 = (c0 & 3) * 8;
    const int r1 = c1 >> 2, k81 = (c1 & 3) * 8;

    for (int k0 = 0; k0 < Kd; k0 += 64) {
        __syncthreads();   // protect prior iter's fragment reads
        cp16_async(A + (size_t)r0 * lda + k0 + k80,      sA0 + c0 * 8);
        cp16_async(A + (size_t)r1 * lda + k0 + k81,      sA0 + c1 * 8);
        cp16_async(A + (size_t)r0 * lda + k0 + 32 + k80, sA1 + c0 * 8);
        cp16_async(A + (size_t)r1 * lda + k0 + 32 + k81, sA1 + c1 * 8);
        cp16_async(B + (size_t)r0 * ldb + k0 + k80,      sB0 + c0 * 8);
        cp16_async(B + (size_t)r1 * ldb + k0 + k81,      sB0 + c1 * 8);
        cp16_async(B + (size_t)r0 * ldb + k0 + 32 + k80, sB1 + c0 * 8);
        cp16_async(B + (size_t)r1 * ldb + k0 + 32 + k81, sB1 + c1 * 8);
        __syncthreads();   // compiler drains vmcnt(0) here
#pragma unroll
        for (int half = 0; half < 2; ++half) {
            const short* pa = half ? sA1 : sA0;
            const short* pb = half ? sB1 : sB0;
            bf16x8 af[4], bfr[4];
#pragma unroll
            for (int i = 0; i < 4; ++i)
                af[i] = *(const bf16x8*)&pa[(wr + i * 16 + lr) * 32 + quad * 8];
#pragma unroll
            for (int j = 0; j < 4; ++j)
                bfr[j] = *(const bf16x8*)&pb[(wc + j * 16 + lr) * 32 + quad * 8];
#pragma unroll
            for (int i = 0; i < 4; ++i)
#pragma unroll
                for (int j = 0; j < 4; ++j)
                    acc[i * 4 + j] = __builtin_amdgcn_mfma_f32_16x16x32_bf16(af[i], bfr[j], acc[i * 4 + j], 0, 0, 0);
        }
    }
}

__device__ inline void store_out(float* p, float v) { *p = v; }
__device__ inline void store_out(short* p, float v) { *p = f2bf(v); }

template <typename OutT>
__device__ inline void store_tile128(OutT* C, int ldc, const f32x4* acc) {
    const int lane = threadIdx.x & 63, wv = threadIdx.x >> 6;
    const int quad = lane >> 4, lr = lane & 15;
    const int wr = (wv >> 1) * 64, wc = (wv & 1) * 64;
#pragma unroll
    for (int i = 0; i < 4; ++i)
#pragma unroll
        for (int j = 0; j < 4; ++j)
#pragma unroll
            for (int r = 0; r < 4; ++r)
                store_out(&C[(size_t)(wr + i * 16 + quad * 4 + r) * ldc + wc + j * 16 + lr],
                          acc[i * 4 + j][r]);
}

// ---------------- unified projections ----------------
// grid 1536 blocks:
//   0..1023   : row-major Q|K: mt = bid>>3 (0..127), by = bid&7 (<4 -> Q cols, else K cols)
//               K blocks additionally scatter Kt[b][f][t] from registers.
//   1024..1535: Vt (feature-major): r = bid-1024 -> b = r&3, tt = (r>>2)&31, ft = r>>7
__global__ __launch_bounds__(256, 4) void proj_all(const short* __restrict__ Xb,
                                                   const short* __restrict__ W4T,
                                                   short* __restrict__ Qb, short* __restrict__ Kb,
                                                   short* __restrict__ Vt, short* __restrict__ Kt) {
    LDS_DECL;
    f32x4 acc[16];
#pragma unroll
    for (int i = 0; i < 16; ++i) acc[i] = (f32x4){0.f, 0.f, 0.f, 0.f};
    const int bid = blockIdx.x;
    const int lane = threadIdx.x & 63, wv = threadIdx.x >> 6;
    const int quad = lane >> 4, lr = lane & 15;
    const int wr = (wv >> 1) * 64, wc = (wv & 1) * 64;
    if (bid < 1024) {
        const int mt = bid >> 3, by = bid & 7;
        const short* At = Xb + (size_t)mt * 128 * 512;
        const short* Bt = W4T + (size_t)by * 128 * 512;   // by<4: Wq cols, else Wk cols
        short* Ct = ((by < 4) ? Qb : Kb) + (size_t)mt * 128 * 512 + (by & 3) * 128;
        mfma_kloop64(At, 512, Bt, 512, 512, acc, sA0, sA1, sB0, sB1);
        store_tile128(Ct, 512, acc);
        if (by >= 4) {
            // emit Kt[b][f][t] from registers (int2 scatter; block covers full
            // 128-t span per f, so L2 assembles complete lines -> no HBM overfetch)
            const int b = mt >> 5;
            const int t0b = (mt & 31) * 128;
            const int f0 = (by - 4) * 128;
#pragma unroll
            for (int i = 0; i < 4; ++i)
#pragma unroll
                for (int j = 0; j < 4; ++j) {
                    int f = f0 + wc + j * 16 + lr;
                    int tt0 = t0b + wr + i * 16 + quad * 4;
                    short tmp[4];
#pragma unroll
                    for (int r = 0; r < 4; ++r) tmp[r] = f2bf(acc[i * 4 + j][r]);
                    *(int2*)&Kt[((size_t)b * 512 + f) * 4096 + tt0] = *(const int2*)tmp;
                }
        }
    } else {
        const int r = bid - 1024;
        const int b = r & 3, tt = (r >> 2) & 31, ft = r >> 7;
        const short* At = W4T + (size_t)2 * 262144 + (size_t)ft * 128 * 512;   // Wv
        const short* Bt = Xb + ((size_t)b * 4096 + tt * 128) * 512;
        short* Ct = Vt + (size_t)b * 512 * 4096 + (size_t)ft * 128 * 4096 + tt * 128;
        mfma_kloop64(At, 512, Bt, 512, 512, acc, sA0, sA1, sB0, sB1);
        store_tile128(Ct, 4096, acc);
    }
}

// ---------------- chunked linear attention (C=256, 16 chunks/batch) ----------------

// AM[b,c][v][k] = sum_{t in chunk c} Vt[b][v][t] * Kt[b][k][t]; grid (4,4,64)
__global__ __launch_bounds__(256, 4) void phaseA(const short* __restrict__ Vt,
                                                 const short* __restrict__ Kt,
                                                 short* __restrict__ AM) {
    LDS_DECL;
    const int bc = blockIdx.z, b = bc >> 4, c = bc & 15;
    const short* Ap = Vt + ((size_t)b * 512 + blockIdx.x * 128) * 4096 + c * 256;
    const short* Bp = Kt + ((size_t)b * 512 + blockIdx.y * 128) * 4096 + c * 256;
    short* Cp = AM + (size_t)bc * 262144 + (size_t)blockIdx.x * 128 * 512 + blockIdx.y * 128;
    f32x4 acc[16];
#pragma unroll
    for (int i = 0; i < 16; ++i) acc[i] = (f32x4){0.f, 0.f, 0.f, 0.f};
    mfma_kloop64(Ap, 4096, Bp, 4096, 256, acc, sA0, sA1, sB0, sB1);
    store_tile128(Cp, 512, acc);
}

// merged: blocks 0..511 = exclusive prefix scan over chunks of AM (memory-bound);
//         blocks 512..767 = P = tril(Q_c K_c^T) (compute-bound) -- independent, overlap.
__global__ __launch_bounds__(256, 4) void scan_phaseS(short* __restrict__ AM,
                                                      const short* __restrict__ Q,
                                                      const short* __restrict__ K,
                                                      short* __restrict__ P) {
    LDS_DECL;
    if (blockIdx.x < 512) {
        int i = blockIdx.x * 256 + threadIdx.x;   // 0..131071
        int b = i >> 15;
        int vk8 = i & 32767;
        size_t base = (size_t)b * 16 * 262144 + (size_t)vk8 * 8;
        float acc[8];
#pragma unroll
        for (int s = 0; s < 8; ++s) acc[s] = 0.f;
        for (int c = 0; c < 16; ++c) {
            short* p = AM + base + (size_t)c * 262144;
            short in8[8];
            *(int4*)in8 = *(const int4*)p;
            short out8[8];
#pragma unroll
            for (int s = 0; s < 8; ++s) out8[s] = f2bf(acc[s]);
            *(int4*)p = *(const int4*)out8;
#pragma unroll
            for (int s = 0; s < 8; ++s) acc[s] += bf2f(in8[s]);
        }
        return;
    }
    const int e = blockIdx.x - 512;               // 0..255
    const int bc = e >> 2, mt = e & 1, nt = (e >> 1) & 1;
    if (mt < nt) return;                          // dead tile (never read)
    const int b = bc >> 4, c = bc & 15;
    short* Pt = P + (size_t)bc * 65536 + (size_t)mt * 128 * 256 + nt * 128;
    const short* Ap = Q + ((size_t)(b * 4096 + c * 256 + mt * 128)) * 512;
    const short* Bp = K + ((size_t)(b * 4096 + c * 256 + nt * 128)) * 512;
    f32x4 acc[16];
#pragma unroll
    for (int i = 0; i < 16; ++i) acc[i] = (f32x4){0.f, 0.f, 0.f, 0.f};
    mfma_kloop64(Ap, 512, Bp, 512, 512, acc, sA0, sA1, sB0, sB1);
    const int lane = threadIdx.x & 63, wv = threadIdx.x >> 6;
    const int quad = lane >> 4, lr = lane & 15;
    const int wr = (wv >> 1) * 64, wc = (wv & 1) * 64;
    const bool diag = (mt == nt);
#pragma unroll
    for (int i = 0; i < 4; ++i)
#pragma unroll
        for (int j = 0; j < 4; ++j)
#pragma unroll
            for (int r = 0; r < 4; ++r) {
                int t = wr + i * 16 + quad * 4 + r;
                int jj = wc + j * 16 + lr;
                float v = (!diag || jj <= t) ? acc[i * 4 + j][r] : 0.f;
                Pt[(size_t)t * 256 + jj] = f2bf(v);
            }
}

// Y_c = Q_c * Mpre_c^T + tril(P_c) * V_c ; grid (2 mt, 4 nt, 64 bc)
__global__ __launch_bounds__(256, 4) void phaseY(const short* __restrict__ Q,
                                                 const short* __restrict__ Mpre,
                                                 const short* __restrict__ P,
                                                 const short* __restrict__ Vt,
                                                 short* __restrict__ Y) {
    LDS_DECL;
    const int bc = blockIdx.z, b = bc >> 4, c = bc & 15;
    const int mt = blockIdx.x, nt = blockIdx.y;
    f32x4 acc[16];
#pragma unroll
    for (int i = 0; i < 16; ++i) acc[i] = (f32x4){0.f, 0.f, 0.f, 0.f};
    // inter: Y[t][v] += sum_k Q[t][k] * Mpre[v][k]
    const short* Ai = Q + ((size_t)(b * 4096 + c * 256 + mt * 128)) * 512;
    const short* Bi = Mpre + (size_t)bc * 262144 + (size_t)nt * 128 * 512;
    mfma_kloop64(Ai, 512, Bi, 512, 512, acc, sA0, sA1, sB0, sB1);
    // intra: Y[t][v] += sum_j P[t][j] * Vt[v][j]; for mt=0 only j<128 nonzero
    const short* Ap = P + (size_t)bc * 65536 + (size_t)mt * 128 * 256;
    const short* Bv = Vt + ((size_t)b * 512 + nt * 128) * 4096 + c * 256;
    mfma_kloop64(Ap, 256, Bv, 4096, (mt + 1) * 128, acc, sA0, sA1, sB0, sB1);
    short* Cp = Y + ((size_t)(b * 4096 + c * 256 + mt * 128)) * 512 + nt * 128;
    store_tile128(Cp, 512, acc);
}

// generic C[M,N] = A . Bt^T (output projection)
template <typename OutT>
__global__ __launch_bounds__(256, 4) void gemm128(const short* __restrict__ A, int lda,
                                                  const short* __restrict__ B, int ldb,
                                                  OutT* __restrict__ C, int ldc, int Kd) {
    LDS_DECL;
    const short* At = A + (size_t)blockIdx.x * 128 * lda;
    const short* Bt = B + (size_t)blockIdx.y * 128 * ldb;
    OutT* Ct = C + (size_t)blockIdx.x * 128 * ldc + blockIdx.y * 128;
    f32x4 acc[16];
#pragma unroll
    for (int i = 0; i < 16; ++i) acc[i] = (f32x4){0.f, 0.f, 0.f, 0.f};
    mfma_kloop64(At, lda, Bt, ldb, Kd, acc, sA0, sA1, sB0, sB1);
    store_tile128(Ct, ldc, acc);
}

// ---------------- host ----------------

extern "C" void kernel_launch(void* const* d_in, const int* in_sizes, int n_in,
                              void* d_out, int out_size, void* d_ws, size_t ws_size,
                              hipStream_t stream) {
    const float* x  = (const float*)d_in[0];
    const float* Wq = (const float*)d_in[1];
    const float* Wk = (const float*)d_in[2];
    const float* Wv = (const float*)d_in[3];
    const float* Wo = (const float*)d_in[4];
    float* out = (float*)d_out;

    const size_t NTD = 16384 * 512;   // 8,388,608 elems

    short* ws  = (short*)d_ws;
    short* Xb  = ws;                  // 8.39M
    short* Qb  = Xb + NTD;
    short* Kb  = Qb + NTD;
    short* Kt  = Kb + NTD;
    short* Vt  = Kt + NTD;
    short* P   = Vt + NTD;            // 4.19M
    short* W4T = P + 4194304;         // 1.05M : WqT|WkT|WvT|WoT
    short* AM  = W4T + 1048576;       // 16.78M
    short* Yb  = Kb;                  // Kb dead after scan_phaseS

    short* WoT = W4T + 3 * 262144;

    prep_kernel<<<12288, 256, 0, stream>>>(x, Xb, Wq, Wk, Wv, Wo, W4T);
    proj_all<<<1536, 256, 0, stream>>>(Xb, W4T, Qb, Kb, Vt, Kt);
    phaseA<<<dim3(4, 4, 64), 256, 0, stream>>>(Vt, Kt, AM);
    scan_phaseS<<<768, 256, 0, stream>>>(AM, Qb, Kb, P);
    phaseY<<<dim3(2, 4, 64), 256, 0, stream>>>(Qb, AM, P, Vt, Yb);
    gemm128<float><<<dim3(128, 4), 256, 0, stream>>>(Yb, 512, WoT, 512, out, 512, 512);
}